// Round 5
// baseline (254.019 us; speedup 1.0000x reference)
//
#include <hip/hip_runtime.h>

// db2 filters, pre-flipped (cross-correlation form used by ptwt)
#define F_LO0 0.4829629131445341f
#define F_LO1 0.8365163037378079f
#define F_LO2 0.22414386804185735f
#define F_LO3 (-0.12940952255092145f)
#define F_HI0 (-0.12940952255092145f)
#define F_HI1 (-0.22414386804185735f)
#define F_HI2 0.8365163037378079f
#define F_HI3 (-0.4829629131445341f)

__device__ __forceinline__ int reflect_idx(int r, int n) {
    r = (r < 0) ? -r : r;
    r = (r >= n) ? 2 * n - 2 - r : r;
    return r;
}

// Fully fused 3-level WPT + weighted squared-sum reduction.
// Two-pass separable filtering per level; every coefficient plane is stored
// even/odd-column split so all LDS gathers are stride-1 across lanes.
// One block = 8x8 tile of the 66x66 level-3 grid for one image.
//
// Region sA (6084 f): stage0 E0/O0 (78x39 each, stride 39)
//                     -> L1 bands b in {0..3}: base b*1444, E 38x19 (+0), O (+722)
//                     -> L2 planes p in {0..15}: base p*324, E 18x9 (+0), O (+162)
// Region sB (6084 f): h1 lo/hi (78x39 layout, lo +0 / hi +3042)
//                     -> h2 per band b: base b*1444, lo 38x19 (+0), hi (+722)
//                     -> h3 per plane p: base p*324, lo 18x9 (+0), hi (+162)
__global__ void __launch_bounds__(256) k_wpt_fused(
    const float* __restrict__ p, const float* __restrict__ t,
    float* __restrict__ out_sum, float inv_den) {
    constexpr int N0 = 512, N1 = 257, N2 = 130, N3 = 66;

    __shared__ float sA[6084];
    __shared__ float sB[6084];
    __shared__ float wsum[4];

    // XCD-chunked swizzle: 15552 = 8 * 1944 (bijective)
    int bid = blockIdx.x;
    int swz = (bid & 7) * (int)(gridDim.x >> 3) + (bid >> 3);
    int img = swz / 81;
    int tt = swz - img * 81;
    int TA = (tt / 9) * 8;
    int TB = (tt % 9) * 8;

    const int tid = threadIdx.x;
    const size_t ibase = (size_t)img * (N0 * N0);

    const int O0r = 8 * TA - 14, O0c = 8 * TB - 14;
    const int O1r = 4 * TA - 6, O1c = 4 * TB - 6;
    const int O2r = 2 * TA - 2, O2c = 2 * TB - 2;

    const bool edge0 = (O0r < 0) || (O0r + 77 > 511) || (O0c < 0) || (O0c + 77 > 511);
    const bool edge1 = (O1r < 0) || (O1r + 37 > 256) || (O1c < 0) || (O1c + 37 > 256);
    const bool edge2 = (O2r < 0) || (O2r + 17 > 129) || (O2c < 0) || (O2c + 17 > 129);

    // ---- stage 0: diff tile, even/odd split. 78 rows x 39 pairs = 3042 ----
    if (!edge0) {
        const float* prow = p + ibase + (size_t)O0r * N0 + O0c;
        const float* trow = t + ibase + (size_t)O0r * N0 + O0c;
#pragma unroll
        for (int it = 0; it < 12; ++it) {
            int e = it * 256 + tid;
            if (e < 3042) {
                unsigned r = (unsigned)e / 39u;
                int k = e - (int)(39u * r);
                const float2 pv = *(const float2*)(prow + (size_t)r * N0 + 2 * k);
                const float2 tv = *(const float2*)(trow + (size_t)r * N0 + 2 * k);
                sA[e] = pv.x - tv.x;          // E0[r*39+k] == e
                sA[e + 3042] = pv.y - tv.y;   // O0
            }
        }
    } else {
#pragma unroll
        for (int it = 0; it < 12; ++it) {
            int e = it * 256 + tid;
            if (e < 3042) {
                unsigned r = (unsigned)e / 39u;
                int k = e - (int)(39u * r);
                int rr = reflect_idx(O0r + (int)r, N0);
                int c0 = reflect_idx(O0c + 2 * k, N0);
                int c1 = reflect_idx(O0c + 2 * k + 1, N0);
                const float* pr = p + ibase + (size_t)rr * N0;
                const float* tr = t + ibase + (size_t)rr * N0;
                sA[e] = pr[c0] - tr[c0];
                sA[e + 3042] = pr[c1] - tr[c1];
            }
        }
    }
    __syncthreads();

    // ---- h1: horizontal filter, 78 rows x 38 cols -> sB lo/hi (stride 39) ----
#pragma unroll
    for (int it = 0; it < 12; ++it) {
        int e = it * 256 + tid;
        if (e < 2964) {
            unsigned r = (unsigned)e / 38u;
            int a0 = e + (int)r;  // r*39 + c
            float Ec = sA[a0], Ec1 = sA[a0 + 1];
            float Oc = sA[a0 + 3042], Oc1 = sA[a0 + 3043];
            sB[a0] = F_LO0 * Ec + F_LO1 * Oc + F_LO2 * Ec1 + F_LO3 * Oc1;
            sB[a0 + 3042] = F_HI0 * Ec + F_HI1 * Oc + F_HI2 * Ec1 + F_HI3 * Oc1;
        }
    }
    __syncthreads();

    // ---- v1: vertical filter, 38x38 -> sA L1 band planes (E/O split) ----
#pragma unroll
    for (int it = 0; it < 6; ++it) {
        int e = it * 256 + tid;
        if (e < 1444) {
            unsigned r2 = (unsigned)e / 38u;
            int c = e - (int)(38u * r2);
            int base = e + (int)(40u * r2);  // 78*r2 + c (rows at stride 39)
            float l0 = sB[base], l1 = sB[base + 39], l2 = sB[base + 78], l3 = sB[base + 117];
            float h0 = sB[base + 3042], h1 = sB[base + 3081], h2 = sB[base + 3120], h3 = sB[base + 3159];
            float b0 = F_LO0 * l0 + F_LO1 * l1 + F_LO2 * l2 + F_LO3 * l3;
            float b1 = F_HI0 * l0 + F_HI1 * l1 + F_HI2 * l2 + F_HI3 * l3;
            float b2 = F_LO0 * h0 + F_LO1 * h1 + F_LO2 * h2 + F_LO3 * h3;
            float b3 = F_HI0 * h0 + F_HI1 * h1 + F_HI2 * h2 + F_HI3 * h3;
            int wa = (int)r2 * 19 + (c >> 1) + (c & 1) * 722;
            sA[wa] = b0;
            sA[wa + 1444] = b1;
            sA[wa + 2888] = b2;
            sA[wa + 4332] = b3;
        }
    }
    __syncthreads();
    if (edge1) {  // patch reflected slots of the L1 tile
        for (int it = 0; it < 6; ++it) {
            int e = it * 256 + tid;
            if (e < 1444) {
                unsigned lr = (unsigned)e / 38u;
                int lc = e - (int)(38u * lr);
                int sr = reflect_idx(O1r + (int)lr, N1) - O1r;
                int sc = reflect_idx(O1c + lc, N1) - O1c;
                if ((sr != (int)lr || sc != lc) && (unsigned)sr < 38u && (unsigned)sc < 38u) {
                    int d = (int)lr * 19 + (lc >> 1) + (lc & 1) * 722;
                    int s = sr * 19 + (sc >> 1) + (sc & 1) * 722;
                    sA[d] = sA[s];
                    sA[d + 1444] = sA[s + 1444];
                    sA[d + 2888] = sA[s + 2888];
                    sA[d + 4332] = sA[s + 4332];
                }
            }
        }
        __syncthreads();
    }

    // ---- h2: 4 bands x 38 rows x 18 cols -> sB (lo/hi per band) ----
#pragma unroll
    for (int it = 0; it < 11; ++it) {
        int e = it * 256 + tid;
        if (e < 2736) {
            unsigned b = (unsigned)e / 684u;
            unsigned rem = (unsigned)e - 684u * b;
            unsigned r = rem / 18u;
            int c2 = (int)rem - (int)(18u * r);
            int ra = (int)(b * 1444u + r * 19u) + c2;
            float Ec = sA[ra], Ec1 = sA[ra + 1];
            float Oc = sA[ra + 722], Oc1 = sA[ra + 723];
            sB[ra] = F_LO0 * Ec + F_LO1 * Oc + F_LO2 * Ec1 + F_LO3 * Oc1;
            sB[ra + 722] = F_HI0 * Ec + F_HI1 * Oc + F_HI2 * Ec1 + F_HI3 * Oc1;
        }
    }
    __syncthreads();

    // ---- v2: 4 bands x 18x18 -> sA L2 planes (E/O split) ----
#pragma unroll
    for (int it = 0; it < 6; ++it) {
        int e = it * 256 + tid;
        if (e < 1296) {
            unsigned b = (unsigned)e / 324u;
            unsigned rem = (unsigned)e - 324u * b;
            unsigned r2 = rem / 18u;
            int c = (int)rem - (int)(18u * r2);
            int base = (int)(b * 1444u + 38u * r2) + c;
            float l0 = sB[base], l1 = sB[base + 19], l2 = sB[base + 38], l3 = sB[base + 57];
            float h0 = sB[base + 722], h1 = sB[base + 741], h2 = sB[base + 760], h3 = sB[base + 779];
            float b0 = F_LO0 * l0 + F_LO1 * l1 + F_LO2 * l2 + F_LO3 * l3;
            float b1 = F_HI0 * l0 + F_HI1 * l1 + F_HI2 * l2 + F_HI3 * l3;
            float b2 = F_LO0 * h0 + F_LO1 * h1 + F_LO2 * h2 + F_LO3 * h3;
            float b3 = F_HI0 * h0 + F_HI1 * h1 + F_HI2 * h2 + F_HI3 * h3;
            int wa = (int)(b * 1296u + r2 * 9u) + (c >> 1) + (c & 1) * 162;
            sA[wa] = b0;
            sA[wa + 324] = b1;
            sA[wa + 648] = b2;
            sA[wa + 972] = b3;
        }
    }
    __syncthreads();
    if (edge2) {  // patch reflected slots of the L2 tile
        for (int it = 0; it < 2; ++it) {
            int e = it * 256 + tid;
            if (e < 324) {
                unsigned lr = (unsigned)e / 18u;
                int lc = e - (int)(18u * lr);
                int sr = reflect_idx(O2r + (int)lr, N2) - O2r;
                int sc = reflect_idx(O2c + lc, N2) - O2c;
                if ((sr != (int)lr || sc != lc) && (unsigned)sr < 18u && (unsigned)sc < 18u) {
                    int d = (int)lr * 9 + (lc >> 1) + (lc & 1) * 162;
                    int s = sr * 9 + (sc >> 1) + (sc & 1) * 162;
#pragma unroll
                    for (int pp = 0; pp < 16; ++pp) sA[d + 324 * pp] = sA[s + 324 * pp];
                }
            }
        }
        __syncthreads();
    }

    // ---- h3: 16 planes x 18 rows x 8 cols -> sB (lo/hi per plane, stride 9) ----
#pragma unroll
    for (int it = 0; it < 9; ++it) {
        int e = it * 256 + tid;
        if (e < 2304) {
            unsigned pl = (unsigned)e / 144u;
            unsigned rem = (unsigned)e - 144u * pl;
            unsigned r = rem >> 3;
            int c3 = (int)(rem & 7u);
            int ra = (int)(pl * 324u + r * 9u) + c3;
            float Ec = sA[ra], Ec1 = sA[ra + 1];
            float Oc = sA[ra + 162], Oc1 = sA[ra + 163];
            sB[ra] = F_LO0 * Ec + F_LO1 * Oc + F_LO2 * Ec1 + F_LO3 * Oc1;
            sB[ra + 162] = F_HI0 * Ec + F_HI1 * Oc + F_HI2 * Ec1 + F_HI3 * Oc1;
        }
    }
    __syncthreads();

    // ---- v3: 16 planes x 8x8, square + weight + accumulate ----
    float local = 0.f;
#pragma unroll
    for (int it = 0; it < 4; ++it) {
        int e = it * 256 + tid;  // < 1024
        int pl = e >> 6;
        int pos = e & 63;
        int i = pos >> 3;
        int j = pos & 7;
        int base = pl * 324 + 18 * i + j;  // 9*(2i+u)+j rows
        float l0 = sB[base], l1 = sB[base + 9], l2 = sB[base + 18], l3 = sB[base + 27];
        float h0 = sB[base + 162], h1 = sB[base + 171], h2 = sB[base + 180], h3 = sB[base + 189];
        float o0 = F_LO0 * l0 + F_LO1 * l1 + F_LO2 * l2 + F_LO3 * l3;
        float o1 = F_HI0 * l0 + F_HI1 * l1 + F_HI2 * l2 + F_HI3 * l3;
        float o2 = F_LO0 * h0 + F_LO1 * h1 + F_LO2 * h2 + F_LO3 * h3;
        float o3 = F_HI0 * h0 + F_HI1 * h1 + F_HI2 * h2 + F_HI3 * h3;
        if (TA + i < N3 && TB + j < N3) {
            float w0 = (pl == 0) ? 0.5f : 1.0f;
            local += w0 * o0 * o0 + o1 * o1 + o2 * o2 + o3 * o3;
        }
    }

    // block reduction: 256 threads = 4 waves, one atomic per block
#pragma unroll
    for (int off = 32; off > 0; off >>= 1) local += __shfl_down(local, off, 64);
    int wave = tid >> 6;
    if ((tid & 63) == 0) wsum[wave] = local;
    __syncthreads();
    if (tid == 0) {
        float s = (wsum[0] + wsum[1] + wsum[2] + wsum[3]) * inv_den;
        atomicAdd(out_sum, s);
    }
}

extern "C" void kernel_launch(void* const* d_in, const int* in_sizes, int n_in,
                              void* d_out, int out_size, void* d_ws, size_t ws_size,
                              hipStream_t stream) {
    const float* preds = (const float*)d_in[0];
    const float* targets = (const float*)d_in[1];
    float* out = (float*)d_out;

    hipMemsetAsync(d_out, 0, sizeof(float), stream);

    const float inv_den = 1.0f / (192.0f * 66.0f * 66.0f);
    const int nblk = 192 * 9 * 9;  // 15552, divisible by 8

    k_wpt_fused<<<dim3(nblk), dim3(256), 0, stream>>>(preds, targets, out, inv_den);
}

// Round 6
// 243.641 us; speedup vs baseline: 1.0426x; 1.0426x over previous
//
#include <hip/hip_runtime.h>

// db2 filters, pre-flipped (cross-correlation form used by ptwt)
#define F_LO0 0.4829629131445341f
#define F_LO1 0.8365163037378079f
#define F_LO2 0.22414386804185735f
#define F_LO3 (-0.12940952255092145f)
#define F_HI0 (-0.12940952255092145f)
#define F_HI1 (-0.22414386804185735f)
#define F_HI2 0.8365163037378079f
#define F_HI3 (-0.4829629131445341f)

__device__ __forceinline__ int reflect_idx(int r, int n) {
    r = (r < 0) ? -r : r;
    r = (r >= n) ? 2 * n - 2 - r : r;
    return r;
}

// vertical 4-tap filter on float4 lanes (4 columns at once)
__device__ __forceinline__ float4 vfilt(const float4 a, const float4 b,
                                        const float4 c, const float4 d,
                                        float c0, float c1, float c2, float c3) {
    return make_float4(c0 * a.x + c1 * b.x + c2 * c.x + c3 * d.x,
                       c0 * a.y + c1 * b.y + c2 * c.y + c3 * d.y,
                       c0 * a.z + c1 * b.z + c2 * c.z + c3 * d.z,
                       c0 * a.w + c1 * b.w + c2 * c.w + c3 * d.w);
}

// horizontal: 12 floats (x0|x1|x2), outputs d=0..3 use taps starting at 2d (phase 0)
__device__ __forceinline__ void hfilt0(const float4 x0, const float4 x1, const float4 x2,
                                       float4& lo, float4& hi) {
    lo.x = F_LO0 * x0.x + F_LO1 * x0.y + F_LO2 * x0.z + F_LO3 * x0.w;
    lo.y = F_LO0 * x0.z + F_LO1 * x0.w + F_LO2 * x1.x + F_LO3 * x1.y;
    lo.z = F_LO0 * x1.x + F_LO1 * x1.y + F_LO2 * x1.z + F_LO3 * x1.w;
    lo.w = F_LO0 * x1.z + F_LO1 * x1.w + F_LO2 * x2.x + F_LO3 * x2.y;
    hi.x = F_HI0 * x0.x + F_HI1 * x0.y + F_HI2 * x0.z + F_HI3 * x0.w;
    hi.y = F_HI0 * x0.z + F_HI1 * x0.w + F_HI2 * x1.x + F_HI3 * x1.y;
    hi.z = F_HI0 * x1.x + F_HI1 * x1.y + F_HI2 * x1.z + F_HI3 * x1.w;
    hi.w = F_HI0 * x1.z + F_HI1 * x1.w + F_HI2 * x2.x + F_HI3 * x2.y;
}

// phase +2: outputs d use taps starting at 2d+2
__device__ __forceinline__ void hfilt2(const float4 x0, const float4 x1, const float4 x2,
                                       float4& lo, float4& hi) {
    lo.x = F_LO0 * x0.z + F_LO1 * x0.w + F_LO2 * x1.x + F_LO3 * x1.y;
    lo.y = F_LO0 * x1.x + F_LO1 * x1.y + F_LO2 * x1.z + F_LO3 * x1.w;
    lo.z = F_LO0 * x1.z + F_LO1 * x1.w + F_LO2 * x2.x + F_LO3 * x2.y;
    lo.w = F_LO0 * x2.x + F_LO1 * x2.y + F_LO2 * x2.z + F_LO3 * x2.w;
    hi.x = F_HI0 * x0.z + F_HI1 * x0.w + F_HI2 * x1.x + F_HI3 * x1.y;
    hi.y = F_HI0 * x1.x + F_HI1 * x1.y + F_HI2 * x1.z + F_HI3 * x1.w;
    hi.z = F_HI0 * x1.z + F_HI1 * x1.w + F_HI2 * x2.x + F_HI3 * x2.y;
    hi.w = F_HI0 * x2.x + F_HI1 * x2.y + F_HI2 * x2.z + F_HI3 * x2.w;
}

// Fully fused 3-level WPT + weighted squared-sum reduction, float4/b128 version.
// One block = 8x8 tile of the 66x66 level-3 grid for one image.
// sA: input tile 78x80 (row-parity quad-XOR swizzled) -> L1 bands 4x(38 rows,
//     stride 40, swizzled) -> L2 planes 16x(18 rows, stride 20, no swizzle).
// sB: h1 out lo/hi 78x40 -> h2 out per band lo/hi 38x20 -> h3 out per plane
//     lo/hi 18x8 (plane stride 296 to spread banks).
__global__ void __launch_bounds__(256) k_wpt_fused(
    const float* __restrict__ p, const float* __restrict__ t,
    float* __restrict__ out_sum, float inv_den) {
    constexpr int N0 = 512, N1 = 257, N2 = 130, N3 = 66;

    __shared__ __align__(16) float sA[6240];
    __shared__ __align__(16) float sB[6240];
    __shared__ float wsum[4];

    // XCD-chunked swizzle: 15552 = 8 * 1944 (bijective)
    int bid = blockIdx.x;
    int swz = (bid & 7) * (int)(gridDim.x >> 3) + (bid >> 3);
    int img = swz / 81;
    int tt = swz - img * 81;
    int TA = (tt / 9) * 8;
    int TB = (tt % 9) * 8;

    const int tid = threadIdx.x;
    const size_t ibase = (size_t)img * (N0 * N0);

    const int O0r = 8 * TA - 14, O0c = 8 * TB - 16;  // col origin 16B-aligned
    const int O1r = 4 * TA - 6, O1c = 4 * TB - 6;
    const int O2r = 2 * TA - 2, O2c = 2 * TB - 2;
    const bool edge = (TA == 0) || (TA == 64) || (TB == 0) || (TB == 64);

    // ---- stage 0: diff tile 78 rows x 20 quads, swizzled quad store ----
    if (!edge) {
        const float* __restrict__ pb = p + ibase + (size_t)O0r * N0 + O0c;
        const float* __restrict__ tb = t + ibase + (size_t)O0r * N0 + O0c;
#pragma unroll
        for (int it = 0; it < 7; ++it) {
            int e = it * 256 + tid;
            if (e < 1560) {
                int r = e / 20, q = e - r * 20;
                const float4 pv = *(const float4*)(pb + (size_t)r * N0 + 4 * q);
                const float4 tv = *(const float4*)(tb + (size_t)r * N0 + 4 * q);
                *(float4*)(sA + r * 80 + ((q ^ (r & 1)) << 2)) =
                    make_float4(pv.x - tv.x, pv.y - tv.y, pv.z - tv.z, pv.w - tv.w);
            }
        }
    } else {
#pragma unroll
        for (int it = 0; it < 7; ++it) {
            int e = it * 256 + tid;
            if (e < 1560) {
                int r = e / 20, q = e - r * 20;
                int gr = reflect_idx(O0r + r, N0);
                const float* pr = p + ibase + (size_t)gr * N0;
                const float* tr = t + ibase + (size_t)gr * N0;
                float v[4];
#pragma unroll
                for (int x = 0; x < 4; ++x) {
                    int gc = reflect_idx(O0c + 4 * q + x, N0);
                    v[x] = pr[gc] - tr[gc];
                }
                *(float4*)(sA + r * 80 + ((q ^ (r & 1)) << 2)) =
                    make_float4(v[0], v[1], v[2], v[3]);
            }
        }
    }
    __syncthreads();

    // ---- h1: 78 rows x 10 groups -> sB lo(0)/hi(3120), stride 40 ----
#pragma unroll
    for (int it = 0; it < 4; ++it) {
        int e = it * 256 + tid;
        if (e < 780) {
            int r = e / 10, k = e - r * 10;
            int r1 = r & 1;
            const float* row = sA + r * 80;
            int q2 = 2 * k + 2; if (q2 > 19) q2 = 18;  // clamp (k=9 tail is masked)
            float4 x0 = *(const float4*)(row + (((2 * k) ^ r1) << 2));
            float4 x1 = *(const float4*)(row + (((2 * k + 1) ^ r1) << 2));
            float4 x2 = *(const float4*)(row + ((q2 ^ r1) << 2));
            float4 lo, hi;
            hfilt2(x0, x1, x2, lo, hi);
            *(float4*)(sB + r * 40 + 4 * k) = lo;
            *(float4*)(sB + 3120 + r * 40 + 4 * k) = hi;
        }
    }
    __syncthreads();

    // ---- v1: 38 rows x 10 groups -> sA L1 bands (stride 40, swizzled) ----
#pragma unroll
    for (int it = 0; it < 2; ++it) {
        int e = it * 256 + tid;
        if (e < 380) {
            int r1 = e / 10, k = e - r1 * 10;
            const float* blo = sB + (2 * r1) * 40 + 4 * k;
            const float* bhi = blo + 3120;
            float4 L0 = *(const float4*)(blo);
            float4 L1v = *(const float4*)(blo + 40);
            float4 L2v = *(const float4*)(blo + 80);
            float4 L3v = *(const float4*)(blo + 120);
            float4 H0 = *(const float4*)(bhi);
            float4 H1 = *(const float4*)(bhi + 40);
            float4 H2 = *(const float4*)(bhi + 80);
            float4 H3 = *(const float4*)(bhi + 120);
            float4 b0 = vfilt(L0, L1v, L2v, L3v, F_LO0, F_LO1, F_LO2, F_LO3);
            float4 b1 = vfilt(L0, L1v, L2v, L3v, F_HI0, F_HI1, F_HI2, F_HI3);
            float4 b2 = vfilt(H0, H1, H2, H3, F_LO0, F_LO1, F_LO2, F_LO3);
            float4 b3 = vfilt(H0, H1, H2, H3, F_HI0, F_HI1, F_HI2, F_HI3);
            int wo = r1 * 40 + ((k ^ (r1 & 1)) << 2);
            *(float4*)(sA + wo) = b0;
            *(float4*)(sA + 1520 + wo) = b1;
            *(float4*)(sA + 3040 + wo) = b2;
            *(float4*)(sA + 4560 + wo) = b3;
        }
    }
    __syncthreads();
    if (edge) {  // patch reflected L1 slots (sources are fixed points: no race)
#pragma unroll
        for (int it = 0; it < 6; ++it) {
            int e = it * 256 + tid;
            if (e < 1444) {
                int lr = e / 38, lc = e - lr * 38;
                int sr = reflect_idx(O1r + lr, N1) - O1r;
                int sc = reflect_idx(O1c + lc, N1) - O1c;
                if ((sr != lr || sc != lc) && (unsigned)sr < 38u && (unsigned)sc < 38u) {
                    int da = lr * 40 + ((((lc >> 2) ^ (lr & 1)) << 2) | (lc & 3));
                    int sa = sr * 40 + ((((sc >> 2) ^ (sr & 1)) << 2) | (sc & 3));
                    sA[da] = sA[sa];
                    sA[1520 + da] = sA[1520 + sa];
                    sA[3040 + da] = sA[3040 + sa];
                    sA[4560 + da] = sA[4560 + sa];
                }
            }
        }
        __syncthreads();
    }

    // ---- h2: 4 bands x 38 rows x 5 groups -> sB band lo(0)/hi(760), stride 20 ----
#pragma unroll
    for (int it = 0; it < 3; ++it) {
        int e = it * 256 + tid;
        if (e < 760) {
            int b = e / 190, rem = e - b * 190;
            int r = rem / 5, k = rem - r * 5;
            int r1 = r & 1;
            const float* row = sA + b * 1520 + r * 40;
            int q2 = 2 * k + 2; if (q2 > 9) q2 = 8;  // clamp (k=4 tail is pad)
            float4 x0 = *(const float4*)(row + (((2 * k) ^ r1) << 2));
            float4 x1 = *(const float4*)(row + (((2 * k + 1) ^ r1) << 2));
            float4 x2 = *(const float4*)(row + ((q2 ^ r1) << 2));
            float4 lo, hi;
            hfilt0(x0, x1, x2, lo, hi);
            float* dst = sB + b * 1520 + r * 20 + 4 * k;
            *(float4*)dst = lo;
            *(float4*)(dst + 760) = hi;
        }
    }
    __syncthreads();

    // ---- v2: 4 bands x 18 rows x 5 groups -> sA L2 planes (stride 20) ----
#pragma unroll
    for (int it = 0; it < 2; ++it) {
        int e = it * 256 + tid;
        if (e < 360) {
            int b = e / 90, rem = e - b * 90;
            int r2 = rem / 5, k = rem - r2 * 5;
            const float* blo = sB + b * 1520 + (2 * r2) * 20 + 4 * k;
            const float* bhi = blo + 760;
            float4 L0 = *(const float4*)(blo);
            float4 L1v = *(const float4*)(blo + 20);
            float4 L2v = *(const float4*)(blo + 40);
            float4 L3v = *(const float4*)(blo + 60);
            float4 H0 = *(const float4*)(bhi);
            float4 H1 = *(const float4*)(bhi + 20);
            float4 H2 = *(const float4*)(bhi + 40);
            float4 H3 = *(const float4*)(bhi + 60);
            float4 b0 = vfilt(L0, L1v, L2v, L3v, F_LO0, F_LO1, F_LO2, F_LO3);
            float4 b1 = vfilt(L0, L1v, L2v, L3v, F_HI0, F_HI1, F_HI2, F_HI3);
            float4 b2 = vfilt(H0, H1, H2, H3, F_LO0, F_LO1, F_LO2, F_LO3);
            float4 b3 = vfilt(H0, H1, H2, H3, F_HI0, F_HI1, F_HI2, F_HI3);
            float* dst = sA + (b * 4) * 360 + r2 * 20 + 4 * k;
            *(float4*)(dst) = b0;
            *(float4*)(dst + 360) = b1;
            *(float4*)(dst + 720) = b2;
            *(float4*)(dst + 1080) = b3;
        }
    }
    __syncthreads();
    if (edge) {  // patch reflected L2 slots
#pragma unroll
        for (int it = 0; it < 2; ++it) {
            int e = it * 256 + tid;
            if (e < 324) {
                int lr = e / 18, lc = e - lr * 18;
                int sr = reflect_idx(O2r + lr, N2) - O2r;
                int sc = reflect_idx(O2c + lc, N2) - O2c;
                if ((sr != lr || sc != lc) && (unsigned)sr < 18u && (unsigned)sc < 18u) {
                    int d = lr * 20 + lc;
                    int s = sr * 20 + sc;
#pragma unroll
                    for (int pp = 0; pp < 16; ++pp) sA[d + 360 * pp] = sA[s + 360 * pp];
                }
            }
        }
        __syncthreads();
    }

    // ---- h3: 16 planes x 18 rows x 2 groups -> sB plane stride 296, lo(0)/hi(148) ----
#pragma unroll
    for (int it = 0; it < 3; ++it) {
        int e = it * 256 + tid;
        if (e < 576) {
            int pl = e / 36, rem = e - pl * 36;
            int r = rem >> 1, k = rem & 1;
            const float* row = sA + pl * 360 + r * 20 + 8 * k;
            float4 x0 = *(const float4*)(row);
            float4 x1 = *(const float4*)(row + 4);
            float4 x2 = *(const float4*)(row + 8);  // tail elements unused for valid outs
            float4 lo, hi;
            hfilt0(x0, x1, x2, lo, hi);
            float* dst = sB + pl * 296 + r * 8 + 4 * k;
            *(float4*)dst = lo;
            *(float4*)(dst + 148) = hi;
        }
    }
    __syncthreads();

    // ---- v3: 16 planes x 8 rows x 2 groups, square + weight + accumulate ----
    float local = 0.f;
    {
        int e = tid;
        int pl = e >> 4;
        int i = (e >> 1) & 7;
        int k = e & 1;
        const float* blo = sB + pl * 296 + (2 * i) * 8 + 4 * k;
        const float* bhi = blo + 148;
        float4 L0 = *(const float4*)(blo);
        float4 L1v = *(const float4*)(blo + 8);
        float4 L2v = *(const float4*)(blo + 16);
        float4 L3v = *(const float4*)(blo + 24);
        float4 H0 = *(const float4*)(bhi);
        float4 H1 = *(const float4*)(bhi + 8);
        float4 H2 = *(const float4*)(bhi + 16);
        float4 H3 = *(const float4*)(bhi + 24);
        float4 o0 = vfilt(L0, L1v, L2v, L3v, F_LO0, F_LO1, F_LO2, F_LO3);
        float4 o1 = vfilt(L0, L1v, L2v, L3v, F_HI0, F_HI1, F_HI2, F_HI3);
        float4 o2 = vfilt(H0, H1, H2, H3, F_LO0, F_LO1, F_LO2, F_LO3);
        float4 o3 = vfilt(H0, H1, H2, H3, F_HI0, F_HI1, F_HI2, F_HI3);
        float w0 = (pl == 0) ? 0.5f : 1.0f;
        int jb = TB + 4 * k;
        if (TA + i < N3) {
            if (jb + 0 < N3) local += w0 * o0.x * o0.x + o1.x * o1.x + o2.x * o2.x + o3.x * o3.x;
            if (jb + 1 < N3) local += w0 * o0.y * o0.y + o1.y * o1.y + o2.y * o2.y + o3.y * o3.y;
            if (jb + 2 < N3) local += w0 * o0.z * o0.z + o1.z * o1.z + o2.z * o2.z + o3.z * o3.z;
            if (jb + 3 < N3) local += w0 * o0.w * o0.w + o1.w * o1.w + o2.w * o2.w + o3.w * o3.w;
        }
    }

    // block reduction: 256 threads = 4 waves, one atomic per block
#pragma unroll
    for (int off = 32; off > 0; off >>= 1) local += __shfl_down(local, off, 64);
    int wave = tid >> 6;
    if ((tid & 63) == 0) wsum[wave] = local;
    __syncthreads();
    if (tid == 0) {
        float s = (wsum[0] + wsum[1] + wsum[2] + wsum[3]) * inv_den;
        atomicAdd(out_sum, s);
    }
}

extern "C" void kernel_launch(void* const* d_in, const int* in_sizes, int n_in,
                              void* d_out, int out_size, void* d_ws, size_t ws_size,
                              hipStream_t stream) {
    const float* preds = (const float*)d_in[0];
    const float* targets = (const float*)d_in[1];
    float* out = (float*)d_out;

    hipMemsetAsync(d_out, 0, sizeof(float), stream);

    const float inv_den = 1.0f / (192.0f * 66.0f * 66.0f);
    const int nblk = 192 * 9 * 9;  // 15552, divisible by 8

    k_wpt_fused<<<dim3(nblk), dim3(256), 0, stream>>>(preds, targets, out, inv_den);
}

// Round 7
// 232.175 us; speedup vs baseline: 1.0941x; 1.0494x over previous
//
#include <hip/hip_runtime.h>

// db2 filters, pre-flipped (cross-correlation form used by ptwt)
#define F_LO0 0.4829629131445341f
#define F_LO1 0.8365163037378079f
#define F_LO2 0.22414386804185735f
#define F_LO3 (-0.12940952255092145f)
#define F_HI0 (-0.12940952255092145f)
#define F_HI1 (-0.22414386804185735f)
#define F_HI2 0.8365163037378079f
#define F_HI3 (-0.4829629131445341f)

__device__ __forceinline__ int reflect_idx(int r, int n) {
    r = (r < 0) ? -r : r;
    r = (r >= n) ? 2 * n - 2 - r : r;
    return r;
}

// vertical 4-tap filter on float4 lanes (4 columns at once)
__device__ __forceinline__ float4 vfilt(const float4 a, const float4 b,
                                        const float4 c, const float4 d,
                                        float c0, float c1, float c2, float c3) {
    return make_float4(c0 * a.x + c1 * b.x + c2 * c.x + c3 * d.x,
                       c0 * a.y + c1 * b.y + c2 * c.y + c3 * d.y,
                       c0 * a.z + c1 * b.z + c2 * c.z + c3 * d.z,
                       c0 * a.w + c1 * b.w + c2 * c.w + c3 * d.w);
}

// horizontal: 12 floats (x0|x1|x2), outputs d=0..3 use taps starting at 2d (phase 0)
__device__ __forceinline__ void hfilt0(const float4 x0, const float4 x1, const float4 x2,
                                       float4& lo, float4& hi) {
    lo.x = F_LO0 * x0.x + F_LO1 * x0.y + F_LO2 * x0.z + F_LO3 * x0.w;
    lo.y = F_LO0 * x0.z + F_LO1 * x0.w + F_LO2 * x1.x + F_LO3 * x1.y;
    lo.z = F_LO0 * x1.x + F_LO1 * x1.y + F_LO2 * x1.z + F_LO3 * x1.w;
    lo.w = F_LO0 * x1.z + F_LO1 * x1.w + F_LO2 * x2.x + F_LO3 * x2.y;
    hi.x = F_HI0 * x0.x + F_HI1 * x0.y + F_HI2 * x0.z + F_HI3 * x0.w;
    hi.y = F_HI0 * x0.z + F_HI1 * x0.w + F_HI2 * x1.x + F_HI3 * x1.y;
    hi.z = F_HI0 * x1.x + F_HI1 * x1.y + F_HI2 * x1.z + F_HI3 * x1.w;
    hi.w = F_HI0 * x1.z + F_HI1 * x1.w + F_HI2 * x2.x + F_HI3 * x2.y;
}

// phase +2: outputs d use taps starting at 2d+2
__device__ __forceinline__ void hfilt2(const float4 x0, const float4 x1, const float4 x2,
                                       float4& lo, float4& hi) {
    lo.x = F_LO0 * x0.z + F_LO1 * x0.w + F_LO2 * x1.x + F_LO3 * x1.y;
    lo.y = F_LO0 * x1.x + F_LO1 * x1.y + F_LO2 * x1.z + F_LO3 * x1.w;
    lo.z = F_LO0 * x1.z + F_LO1 * x1.w + F_LO2 * x2.x + F_LO3 * x2.y;
    lo.w = F_LO0 * x2.x + F_LO1 * x2.y + F_LO2 * x2.z + F_LO3 * x2.w;
    hi.x = F_HI0 * x0.z + F_HI1 * x0.w + F_HI2 * x1.x + F_HI3 * x1.y;
    hi.y = F_HI0 * x1.x + F_HI1 * x1.y + F_HI2 * x1.z + F_HI3 * x1.w;
    hi.z = F_HI0 * x1.z + F_HI1 * x1.w + F_HI2 * x2.x + F_HI3 * x2.y;
    hi.w = F_HI0 * x2.x + F_HI1 * x2.y + F_HI2 * x2.z + F_HI3 * x2.w;
}

// Fully fused 3-level WPT + weighted squared-sum reduction.
// 512 threads/block (8 waves): same 50 KB LDS -> 3 blocks/CU but 24 waves/CU
// (75% occupancy) instead of 12 -- the R6 profile showed a latency limit
// (VALU 40%, LDS ~30%, HBM 9% all idle together at 31.6% occupancy).
__global__ void __launch_bounds__(512, 6) k_wpt_fused(
    const float* __restrict__ p, const float* __restrict__ t,
    float* __restrict__ out_sum, float inv_den) {
    constexpr int N0 = 512, N1 = 257, N2 = 130, N3 = 66;

    __shared__ __align__(16) float sA[6240];
    __shared__ __align__(16) float sB[6240];
    __shared__ float wsum[8];

    // XCD-chunked swizzle: 15552 = 8 * 1944 (bijective)
    int bid = blockIdx.x;
    int swz = (bid & 7) * (int)(gridDim.x >> 3) + (bid >> 3);
    int img = swz / 81;
    int tt = swz - img * 81;
    int TA = (tt / 9) * 8;
    int TB = (tt % 9) * 8;

    const int tid = threadIdx.x;
    const size_t ibase = (size_t)img * (N0 * N0);

    const int O0r = 8 * TA - 14, O0c = 8 * TB - 16;  // col origin 16B-aligned
    const int O1r = 4 * TA - 6, O1c = 4 * TB - 6;
    const int O2r = 2 * TA - 2, O2c = 2 * TB - 2;
    const bool edge = (TA == 0) || (TA == 64) || (TB == 0) || (TB == 64);

    // ---- stage 0: diff tile 78 rows x 20 quads, swizzled quad store ----
    if (!edge) {
        const float* __restrict__ pb = p + ibase + (size_t)O0r * N0 + O0c;
        const float* __restrict__ tb = t + ibase + (size_t)O0r * N0 + O0c;
#pragma unroll
        for (int it = 0; it < 4; ++it) {
            int e = it * 512 + tid;
            if (e < 1560) {
                int r = e / 20, q = e - r * 20;
                const float4 pv = *(const float4*)(pb + (size_t)r * N0 + 4 * q);
                const float4 tv = *(const float4*)(tb + (size_t)r * N0 + 4 * q);
                *(float4*)(sA + r * 80 + ((q ^ (r & 1)) << 2)) =
                    make_float4(pv.x - tv.x, pv.y - tv.y, pv.z - tv.z, pv.w - tv.w);
            }
        }
    } else {
#pragma unroll
        for (int it = 0; it < 4; ++it) {
            int e = it * 512 + tid;
            if (e < 1560) {
                int r = e / 20, q = e - r * 20;
                int gr = reflect_idx(O0r + r, N0);
                const float* pr = p + ibase + (size_t)gr * N0;
                const float* tr = t + ibase + (size_t)gr * N0;
                float v[4];
#pragma unroll
                for (int x = 0; x < 4; ++x) {
                    int gc = reflect_idx(O0c + 4 * q + x, N0);
                    v[x] = pr[gc] - tr[gc];
                }
                *(float4*)(sA + r * 80 + ((q ^ (r & 1)) << 2)) =
                    make_float4(v[0], v[1], v[2], v[3]);
            }
        }
    }
    __syncthreads();

    // ---- h1: 78 rows x 10 groups -> sB lo(0)/hi(3120), stride 40 ----
#pragma unroll
    for (int it = 0; it < 2; ++it) {
        int e = it * 512 + tid;
        if (e < 780) {
            int r = e / 10, k = e - r * 10;
            int r1 = r & 1;
            const float* row = sA + r * 80;
            int q2 = 2 * k + 2; if (q2 > 19) q2 = 18;  // clamp (k=9 tail is masked)
            float4 x0 = *(const float4*)(row + (((2 * k) ^ r1) << 2));
            float4 x1 = *(const float4*)(row + (((2 * k + 1) ^ r1) << 2));
            float4 x2 = *(const float4*)(row + ((q2 ^ r1) << 2));
            float4 lo, hi;
            hfilt2(x0, x1, x2, lo, hi);
            *(float4*)(sB + r * 40 + 4 * k) = lo;
            *(float4*)(sB + 3120 + r * 40 + 4 * k) = hi;
        }
    }
    __syncthreads();

    // ---- v1: 38 rows x 10 groups -> sA L1 bands (stride 40, swizzled) ----
    if (tid < 380) {
        int r1 = tid / 10, k = tid - r1 * 10;
        const float* blo = sB + (2 * r1) * 40 + 4 * k;
        const float* bhi = blo + 3120;
        float4 L0 = *(const float4*)(blo);
        float4 L1v = *(const float4*)(blo + 40);
        float4 L2v = *(const float4*)(blo + 80);
        float4 L3v = *(const float4*)(blo + 120);
        float4 H0 = *(const float4*)(bhi);
        float4 H1 = *(const float4*)(bhi + 40);
        float4 H2 = *(const float4*)(bhi + 80);
        float4 H3 = *(const float4*)(bhi + 120);
        float4 b0 = vfilt(L0, L1v, L2v, L3v, F_LO0, F_LO1, F_LO2, F_LO3);
        float4 b1 = vfilt(L0, L1v, L2v, L3v, F_HI0, F_HI1, F_HI2, F_HI3);
        float4 b2 = vfilt(H0, H1, H2, H3, F_LO0, F_LO1, F_LO2, F_LO3);
        float4 b3 = vfilt(H0, H1, H2, H3, F_HI0, F_HI1, F_HI2, F_HI3);
        int wo = r1 * 40 + ((k ^ (r1 & 1)) << 2);
        *(float4*)(sA + wo) = b0;
        *(float4*)(sA + 1520 + wo) = b1;
        *(float4*)(sA + 3040 + wo) = b2;
        *(float4*)(sA + 4560 + wo) = b3;
    }
    __syncthreads();
    if (edge) {  // patch reflected L1 slots (sources are fixed points: no race)
#pragma unroll
        for (int it = 0; it < 3; ++it) {
            int e = it * 512 + tid;
            if (e < 1444) {
                int lr = e / 38, lc = e - lr * 38;
                int sr = reflect_idx(O1r + lr, N1) - O1r;
                int sc = reflect_idx(O1c + lc, N1) - O1c;
                if ((sr != lr || sc != lc) && (unsigned)sr < 38u && (unsigned)sc < 38u) {
                    int da = lr * 40 + ((((lc >> 2) ^ (lr & 1)) << 2) | (lc & 3));
                    int sa = sr * 40 + ((((sc >> 2) ^ (sr & 1)) << 2) | (sc & 3));
                    sA[da] = sA[sa];
                    sA[1520 + da] = sA[1520 + sa];
                    sA[3040 + da] = sA[3040 + sa];
                    sA[4560 + da] = sA[4560 + sa];
                }
            }
        }
        __syncthreads();
    }

    // ---- h2: 4 bands x 38 rows x 5 groups -> sB band lo(0)/hi(760), stride 20 ----
#pragma unroll
    for (int it = 0; it < 2; ++it) {
        int e = it * 512 + tid;
        if (e < 760) {
            int b = e / 190, rem = e - b * 190;
            int r = rem / 5, k = rem - r * 5;
            int r1 = r & 1;
            const float* row = sA + b * 1520 + r * 40;
            int q2 = 2 * k + 2; if (q2 > 9) q2 = 8;  // clamp (k=4 tail is pad)
            float4 x0 = *(const float4*)(row + (((2 * k) ^ r1) << 2));
            float4 x1 = *(const float4*)(row + (((2 * k + 1) ^ r1) << 2));
            float4 x2 = *(const float4*)(row + ((q2 ^ r1) << 2));
            float4 lo, hi;
            hfilt0(x0, x1, x2, lo, hi);
            float* dst = sB + b * 1520 + r * 20 + 4 * k;
            *(float4*)dst = lo;
            *(float4*)(dst + 760) = hi;
        }
    }
    __syncthreads();

    // ---- v2: 4 bands x 18 rows x 5 groups -> sA L2 planes (stride 20) ----
    if (tid < 360) {
        int b = tid / 90, rem = tid - b * 90;
        int r2 = rem / 5, k = rem - r2 * 5;
        const float* blo = sB + b * 1520 + (2 * r2) * 20 + 4 * k;
        const float* bhi = blo + 760;
        float4 L0 = *(const float4*)(blo);
        float4 L1v = *(const float4*)(blo + 20);
        float4 L2v = *(const float4*)(blo + 40);
        float4 L3v = *(const float4*)(blo + 60);
        float4 H0 = *(const float4*)(bhi);
        float4 H1 = *(const float4*)(bhi + 20);
        float4 H2 = *(const float4*)(bhi + 40);
        float4 H3 = *(const float4*)(bhi + 60);
        float4 b0 = vfilt(L0, L1v, L2v, L3v, F_LO0, F_LO1, F_LO2, F_LO3);
        float4 b1 = vfilt(L0, L1v, L2v, L3v, F_HI0, F_HI1, F_HI2, F_HI3);
        float4 b2 = vfilt(H0, H1, H2, H3, F_LO0, F_LO1, F_LO2, F_LO3);
        float4 b3 = vfilt(H0, H1, H2, H3, F_HI0, F_HI1, F_HI2, F_HI3);
        float* dst = sA + (b * 4) * 360 + r2 * 20 + 4 * k;
        *(float4*)(dst) = b0;
        *(float4*)(dst + 360) = b1;
        *(float4*)(dst + 720) = b2;
        *(float4*)(dst + 1080) = b3;
    }
    __syncthreads();
    if (edge) {  // patch reflected L2 slots
        if (tid < 324) {
            int lr = tid / 18, lc = tid - lr * 18;
            int sr = reflect_idx(O2r + lr, N2) - O2r;
            int sc = reflect_idx(O2c + lc, N2) - O2c;
            if ((sr != lr || sc != lc) && (unsigned)sr < 18u && (unsigned)sc < 18u) {
                int d = lr * 20 + lc;
                int s = sr * 20 + sc;
#pragma unroll
                for (int pp = 0; pp < 16; ++pp) sA[d + 360 * pp] = sA[s + 360 * pp];
            }
        }
        __syncthreads();
    }

    // ---- h3: 16 planes x 18 rows x 2 groups -> sB plane stride 296, lo(0)/hi(148) ----
#pragma unroll
    for (int it = 0; it < 2; ++it) {
        int e = it * 512 + tid;
        if (e < 576) {
            int pl = e / 36, rem = e - pl * 36;
            int r = rem >> 1, k = rem & 1;
            const float* row = sA + pl * 360 + r * 20 + 8 * k;
            float4 x0 = *(const float4*)(row);
            float4 x1 = *(const float4*)(row + 4);
            float4 x2 = *(const float4*)(row + 8);  // tail elements unused for valid outs
            float4 lo, hi;
            hfilt0(x0, x1, x2, lo, hi);
            float* dst = sB + pl * 296 + r * 8 + 4 * k;
            *(float4*)dst = lo;
            *(float4*)(dst + 148) = hi;
        }
    }
    __syncthreads();

    // ---- v3: 16 planes x 8 rows x 2 groups, square + weight + accumulate ----
    float local = 0.f;
    if (tid < 256) {
        int e = tid;
        int pl = e >> 4;
        int i = (e >> 1) & 7;
        int k = e & 1;
        const float* blo = sB + pl * 296 + (2 * i) * 8 + 4 * k;
        const float* bhi = blo + 148;
        float4 L0 = *(const float4*)(blo);
        float4 L1v = *(const float4*)(blo + 8);
        float4 L2v = *(const float4*)(blo + 16);
        float4 L3v = *(const float4*)(blo + 24);
        float4 H0 = *(const float4*)(bhi);
        float4 H1 = *(const float4*)(bhi + 8);
        float4 H2 = *(const float4*)(bhi + 16);
        float4 H3 = *(const float4*)(bhi + 24);
        float4 o0 = vfilt(L0, L1v, L2v, L3v, F_LO0, F_LO1, F_LO2, F_LO3);
        float4 o1 = vfilt(L0, L1v, L2v, L3v, F_HI0, F_HI1, F_HI2, F_HI3);
        float4 o2 = vfilt(H0, H1, H2, H3, F_LO0, F_LO1, F_LO2, F_LO3);
        float4 o3 = vfilt(H0, H1, H2, H3, F_HI0, F_HI1, F_HI2, F_HI3);
        float w0 = (pl == 0) ? 0.5f : 1.0f;
        int jb = TB + 4 * k;
        if (TA + i < N3) {
            if (jb + 0 < N3) local += w0 * o0.x * o0.x + o1.x * o1.x + o2.x * o2.x + o3.x * o3.x;
            if (jb + 1 < N3) local += w0 * o0.y * o0.y + o1.y * o1.y + o2.y * o2.y + o3.y * o3.y;
            if (jb + 2 < N3) local += w0 * o0.z * o0.z + o1.z * o1.z + o2.z * o2.z + o3.z * o3.z;
            if (jb + 3 < N3) local += w0 * o0.w * o0.w + o1.w * o1.w + o2.w * o2.w + o3.w * o3.w;
        }
    }

    // block reduction: 512 threads = 8 waves, one atomic per block
#pragma unroll
    for (int off = 32; off > 0; off >>= 1) local += __shfl_down(local, off, 64);
    int wave = tid >> 6;
    if ((tid & 63) == 0) wsum[wave] = local;
    __syncthreads();
    if (tid == 0) {
        float s = 0.f;
#pragma unroll
        for (int w = 0; w < 8; ++w) s += wsum[w];
        atomicAdd(out_sum, s * inv_den);
    }
}

extern "C" void kernel_launch(void* const* d_in, const int* in_sizes, int n_in,
                              void* d_out, int out_size, void* d_ws, size_t ws_size,
                              hipStream_t stream) {
    const float* preds = (const float*)d_in[0];
    const float* targets = (const float*)d_in[1];
    float* out = (float*)d_out;

    hipMemsetAsync(d_out, 0, sizeof(float), stream);

    const float inv_den = 1.0f / (192.0f * 66.0f * 66.0f);
    const int nblk = 192 * 9 * 9;  // 15552, divisible by 8

    k_wpt_fused<<<dim3(nblk), dim3(512), 0, stream>>>(preds, targets, out, inv_den);
}